// Round 1
// 371.291 us; speedup vs baseline: 1.0091x; 1.0091x over previous
//
#include <hip/hip_runtime.h>

#define EPS 1e-8f
#define BM 256
#define BN 256
#define BK 64

typedef __attribute__((ext_vector_type(8))) short bf16x8;   // 8 bf16 = 4 VGPRs
typedef __attribute__((ext_vector_type(4))) float f32x4;    // MFMA C/D

// RNE float -> bf16 (inputs are finite normals; no NaN handling needed)
__device__ inline unsigned short f2bf(float f) {
    union { float f; unsigned u; } c; c.f = f;
    unsigned u = c.u;
    return (unsigned short)((u + 0x7fffu + ((u >> 16) & 1u)) >> 16);
}

// One wave per row: norms + bf16 conversion. K must be a multiple of 4.
__global__ void prep_kernel(const float* __restrict__ x, unsigned short* __restrict__ xbf,
                            float* __restrict__ norms, int rows, int K) {
    const int row = blockIdx.x * 4 + (threadIdx.x >> 6);
    const int lane = threadIdx.x & 63;
    if (row >= rows) return;
    const float* p = x + (size_t)row * K;
    unsigned short* q = xbf + (size_t)row * K;
    float ss = 0.f;
    for (int base = lane * 4; base < K; base += 256) {
        float4 v = *(const float4*)(p + base);
        ss += v.x * v.x + v.y * v.y + v.z * v.z + v.w * v.w;
        ushort4 o;
        o.x = f2bf(v.x); o.y = f2bf(v.y); o.z = f2bf(v.z); o.w = f2bf(v.w);
        *(ushort4*)(q + base) = o;
    }
#pragma unroll
    for (int off = 32; off > 0; off >>= 1) ss += __shfl_down(ss, off, 64);
    if (lane == 0) norms[row] = sqrtf(ss);
}

#define GLOAD_LDS16(g, l)                                                         \
    __builtin_amdgcn_global_load_lds(                                             \
        (const __attribute__((address_space(1))) unsigned int*)(g),               \
        (__attribute__((address_space(3))) unsigned int*)(l), 16, 0, 0)

// 256x256 tile, BK=64, 8 waves (2M x 4N), 8-phase schedule with counted vmcnt.
// A=[M][K] bf16 (x2), B=[N][K] bf16 (x1). C[m,n] = A[m,:]·B[n,:] / max(nA*nB, eps).
// LDS layout per buffer: [256 rows][8 chunks of 16B], chunk XOR-swizzled by (row&7).
// global_load_lds writes linearly; the per-lane GLOBAL address is pre-swizzled so
// LDS[row][c] = global[row][c ^ (row&7)]; reads apply the same XOR (rule #21).
__global__ __launch_bounds__(512, 2) void gemm_cos_kernel(
    const unsigned short* __restrict__ A, const unsigned short* __restrict__ B,
    const float* __restrict__ nA, const float* __restrict__ nB,
    float* __restrict__ C, int M, int N, int K) {
    __shared__ __align__(16) unsigned short As[2][BM * BK];   // 2 x 32 KiB
    __shared__ __align__(16) unsigned short Bs[2][BN * BK];   // 2 x 32 KiB  (128 KiB total)

    const int tid = threadIdx.x;
    const int w = tid >> 6;          // wave 0..7
    const int lane = tid & 63;
    const int wm = w >> 2;           // 0..1 : 128-row half of the M-tile
    const int wn = w & 3;            // 0..3 : 64-col slice of the N-tile
    const int q = lane >> 4;         // quad
    const int l16 = lane & 15;

    // Bijective XCD-aware swizzle (gridDim.x % 8 == 0 enforced host-side)
    const int cpx = gridDim.x >> 3;
    const int bid = ((int)blockIdx.x & 7) * cpx + ((int)blockIdx.x >> 3);
    const int nbx = N / BN;
    const int by = bid / nbx, bx = bid - by * nbx;
    const int row0 = by * BM, col0 = bx * BN;

    // ---- staging geometry: 1 half-tile (128 rows x 64 cols) = 2 x global_load_lds ----
    // instr j covers rows j*64 + w*8 + (lane>>3); lane chunk = (lane&7) ^ (lane>>3)
    const int srow = (w << 3) + (lane >> 3);        // 0..63
    const int schunk = (lane & 7) ^ (lane >> 3);    // pre-swizzled source chunk
    const unsigned short* gA = A + (size_t)(row0 + srow) * K + schunk * 8;
    const unsigned short* gB = B + (size_t)(col0 + srow) * K + schunk * 8;
    unsigned short* lA0 = &As[0][w * 512];          // wave-uniform LDS base (bytes: w*1024)
    unsigned short* lB0 = &Bs[0][w * 512];

#define STAGE_A(b, h, t_) do {                                                           \
        GLOAD_LDS16(gA + (size_t)((h) * 128) * K + (t_) * BK,                            \
                    lA0 + (b) * 16384 + (h) * 8192);                                     \
        GLOAD_LDS16(gA + (size_t)((h) * 128 + 64) * K + (t_) * BK,                       \
                    lA0 + (b) * 16384 + (h) * 8192 + 4096);                              \
    } while (0)
#define STAGE_B(b, h, t_) do {                                                           \
        GLOAD_LDS16(gB + (size_t)((h) * 128) * K + (t_) * BK,                            \
                    lB0 + (b) * 16384 + (h) * 8192);                                     \
        GLOAD_LDS16(gB + (size_t)((h) * 128 + 64) * K + (t_) * BK,                       \
                    lB0 + (b) * 16384 + (h) * 8192 + 4096);                              \
    } while (0)

    // ---- fragment-read geometry (swizzled chunk = (kk*4+q) ^ (row&7), row&7 == l16&7) ----
    const int arow = wm * 128 + l16;
    const int brow = wn * 64 + l16;
    const int cx = l16 & 7;
    const int k0off = (q ^ cx) * 8;          // kk=0 chunk, in ushort elements
    const int k1off = ((q + 4) ^ cx) * 8;    // kk=1 chunk

    f32x4 acc[8][4] = {};
    bf16x8 bF[4][2], aF[2][2];

    // ---- prologue: A(0), B(0) must land; B(1) stays in flight ----
    STAGE_A(0, 0, 0); STAGE_A(0, 1, 0);
    STAGE_B(0, 0, 0); STAGE_B(0, 1, 0);
    STAGE_B(1, 0, 1); STAGE_B(1, 1, 1);
    asm volatile("s_waitcnt vmcnt(4)" ::: "memory");
    __builtin_amdgcn_s_barrier();
    __builtin_amdgcn_sched_barrier(0);

    const int NT = K / BK;   // >= 3 enforced host-side
    for (int t = 0; t < NT; ++t) {
        const int buf = t & 1;
        const unsigned short* as_ = &As[buf][arow * 64];
        const unsigned short* bs_ = &Bs[buf][brow * 64];
#pragma unroll
        for (int ph = 0; ph < 4; ++ph) {
            // ds-load register subtile: B all 8 frags at ph0, A 4 frags each phase
            if (ph == 0) {
#pragma unroll
                for (int n = 0; n < 4; ++n) {
                    bF[n][0] = *(const bf16x8*)(bs_ + n * 1024 + k0off);
                    bF[n][1] = *(const bf16x8*)(bs_ + n * 1024 + k1off);
                }
            }
#pragma unroll
            for (int mi = 0; mi < 2; ++mi) {
                aF[mi][0] = *(const bf16x8*)(as_ + (ph * 2 + mi) * 1024 + k0off);
                aF[mi][1] = *(const bf16x8*)(as_ + (ph * 2 + mi) * 1024 + k1off);
            }
            // stage 1 half-tile: A(t+1) during ph0/ph1 (other buffer),
            // B(t+2) during ph2/ph3 (this buffer; its old data was consumed at ph0)
            if (ph == 0)      { if (t + 1 < NT) STAGE_A(buf ^ 1, 0, t + 1); }
            else if (ph == 1) { if (t + 1 < NT) STAGE_A(buf ^ 1, 1, t + 1); }
            else if (ph == 2) { if (t + 2 < NT) STAGE_B(buf, 0, t + 2); }
            else              { if (t + 2 < NT) STAGE_B(buf, 1, t + 2); }

            __builtin_amdgcn_s_barrier();
            asm volatile("s_waitcnt lgkmcnt(0)" ::: "memory");
            __builtin_amdgcn_sched_barrier(0);
            __builtin_amdgcn_s_setprio(1);
#pragma unroll
            for (int mi = 0; mi < 2; ++mi)
#pragma unroll
                for (int n = 0; n < 4; ++n) {
                    f32x4 c = acc[ph * 2 + mi][n];
                    c = __builtin_amdgcn_mfma_f32_16x16x32_bf16(aF[mi][0], bF[n][0], c, 0, 0, 0);
                    c = __builtin_amdgcn_mfma_f32_16x16x32_bf16(aF[mi][1], bF[n][1], c, 0, 0, 0);
                    acc[ph * 2 + mi][n] = c;
                }
            __builtin_amdgcn_s_setprio(0);
            if (ph == 3) {
                // once per K-tile; leaves B(t+2)'s 4 loads in flight across the barrier
                if (t < NT - 2) asm volatile("s_waitcnt vmcnt(4)" ::: "memory");
                else            asm volatile("s_waitcnt vmcnt(0)" ::: "memory");
            }
            __builtin_amdgcn_s_barrier();
            __builtin_amdgcn_sched_barrier(0);
        }
    }

    // ---- epilogue: D[row=q*4+r][col=l16] per 16x16 tile (m89/m91-verified layout) ----
    const int crow0 = row0 + wm * 128 + q * 4;
    const int ccol0 = col0 + wn * 64 + l16;
    float rb[4];
#pragma unroll
    for (int n = 0; n < 4; ++n) rb[n] = nB[ccol0 + n * 16];
#pragma unroll
    for (int m = 0; m < 8; ++m) {
#pragma unroll
        for (int r = 0; r < 4; ++r) {
            const int row = crow0 + m * 16 + r;
            const float ra = nA[row];
            float* outp = C + (size_t)row * N + ccol0;
#pragma unroll
            for (int n = 0; n < 4; ++n) {
                float v = acc[m][n][r] / fmaxf(ra * rb[n], EPS);
                __builtin_nontemporal_store(v, outp + n * 16);   // don't evict L2 A/B panels
            }
        }
    }
#undef STAGE_A
#undef STAGE_B
}

// Correctness-guard fallback (weird shapes / tiny ws): naive fp32.
__global__ void naive_kernel(const float* __restrict__ x1, const float* __restrict__ x2,
                             float* __restrict__ out, int N, int M, int K) {
    long long idx = (long long)blockIdx.x * blockDim.x + threadIdx.x;
    if (idx >= (long long)M * N) return;
    int m = (int)(idx / N), n = (int)(idx % N);
    const float* a = x2 + (size_t)m * K;
    const float* b = x1 + (size_t)n * K;
    float dot = 0.f, sa = 0.f, sb = 0.f;
    for (int k = 0; k < K; k++) {
        float av = a[k], bv = b[k];
        dot += av * bv; sa += av * av; sb += bv * bv;
    }
    out[idx] = dot / fmaxf(sqrtf(sa) * sqrtf(sb), EPS);
}

extern "C" void kernel_launch(void* const* d_in, const int* in_sizes, int n_in,
                              void* d_out, int out_size, void* d_ws, size_t ws_size,
                              hipStream_t stream) {
    const float* x1 = (const float*)d_in[0];   // [N][K]
    const float* x2 = (const float*)d_in[1];   // [M][K]
    float* out = (float*)d_out;                // [M][N]
    const int K = 512;
    const int N = in_sizes[0] / K;
    const int M = in_sizes[1] / K;

    const size_t szA = (size_t)M * K * sizeof(unsigned short);
    const size_t szB = (size_t)N * K * sizeof(unsigned short);
    const size_t need = szA + szB + (size_t)(M + N) * sizeof(float);

    const int nwg = (M / BM) * (N / BN);
    const bool fast = (in_sizes[0] % K == 0) && (in_sizes[1] % K == 0) &&
                      (M % BM == 0) && (N % BN == 0) && (K % BK == 0) && (K / BK >= 3) &&
                      (nwg % 8 == 0) &&
                      (need <= ws_size) && ((long long)M * N == (long long)out_size);

    if (fast) {
        unsigned short* Abf = (unsigned short*)d_ws;                       // x2 bf16
        unsigned short* Bbf = (unsigned short*)((char*)d_ws + szA);        // x1 bf16
        float* nA = (float*)((char*)d_ws + szA + szB);                     // ||x2[m]||
        float* nB = nA + M;                                                // ||x1[n]||
        prep_kernel<<<(M + 3) / 4, 256, 0, stream>>>(x2, Abf, nA, M, K);
        prep_kernel<<<(N + 3) / 4, 256, 0, stream>>>(x1, Bbf, nB, N, K);
        gemm_cos_kernel<<<dim3(nwg), 512, 0, stream>>>(Abf, Bbf, nA, nB, out, M, N, K);
    } else {
        long long total = (long long)M * N;
        int blocks = (int)((total + 255) / 256);
        naive_kernel<<<blocks, 256, 0, stream>>>(x1, x2, out, N, M, K);
    }
}